// Round 25
// baseline (455.516 us; speedup 1.0000x reference)
//
#include <hip/hip_runtime.h>
#include <hip/hip_bf16.h>

typedef __attribute__((ext_vector_type(4))) int i32x4;
typedef __attribute__((ext_vector_type(8))) int i32x8;
typedef __attribute__((ext_vector_type(4))) float f32x4;

// exact floor(log2(x)) for x > 0 (handles subnormals)
__device__ __forceinline__ int flog2(float x) {
  unsigned u = __float_as_uint(x);
  int e = (int)((u >> 23) & 255u);
  if (e) return e - 127;
  unsigned m = u & 0x7fffffu;
  return (31 - __clz(m)) - 149;
}

// exact 2^e for e in [-252, 254]
__device__ __forceinline__ float exp2i(int e) {
  int e1 = e >> 1, e2 = e - e1;
  return __uint_as_float((unsigned)(e1 + 127) << 23) *
         __uint_as_float((unsigned)(e2 + 127) << 23);
}

// quantize y (already divided by shared scale) to e2m<MFRAC>, round-half-even, saturate
template <int MFRAC>
__device__ __forceinline__ float qelem(float y, float maxn) {
  float ay = fabsf(y);
  int e = (ay == 0.f) ? 0 : flog2(ay);
  if (e < 0) e = 0;  // min_exp = 0 for ebits=2
  float r = rintf(y * exp2i(MFRAC - e)) * exp2i(e - MFRAC);
  return fminf(fmaxf(r, -maxn), maxn);
}

// general RNE fp32 -> OCP e4m3 encode (|v| <= 448; exact on our folded value grid)
__device__ __forceinline__ unsigned char enc_rne(float v) {
  unsigned u = __float_as_uint(v);
  unsigned s = u >> 31;
  float a = fabsf(v);
  if (a == 0.f) return (unsigned char)(s << 7);
  int e = flog2(a);
  if (e < -6) e = -6;                      // subnormal regime
  int qi = (int)rintf(a * exp2i(3 - e));   // RNE to 3-frac-bit grid -> [0,16]
  if (qi == 0) return (unsigned char)(s << 7);
  if (qi == 16) { qi = 8; e += 1; }
  unsigned exf, m;
  if (qi < 8) { exf = 0u; m = (unsigned)qi; }          // e == -6 subnormal
  else { exf = (unsigned)(e + 7); m = (unsigned)(qi - 8); }
  return (unsigned char)((s << 7) | (exf << 3) | m);
}

// fragment-page swizzle (CONTIGUOUS-LANE layout): 2KB page per (16-row x 128-K block);
// lane l = (row&15) + ((k>>5)&3)*16 holds k-bytes [ (l>>4)*32 , +32 ) CONTIGUOUSLY at
// page + l*32. pa = K/128 pages per row-block.
__device__ __forceinline__ size_t swz(int row, int col, int pa) {
  return ((size_t)((row >> 4) * pa + (col >> 7))) * 2048
       + (size_t)((((row & 15) + (((col >> 5) & 3) << 4)) << 5) + (col & 31));
}

// ------ MX quantization with exponent folding -> fragment-page-swizzled e4m3 bytes ---
template <int MFRAC, int EMAX>
__global__ void quant_fold(const float* __restrict__ in, unsigned char* __restrict__ out,
                           long n4, float maxn, int se0, int kshift, int kmask, int pa) {
  long i = (long)blockIdx.x * blockDim.x + threadIdx.x;
  long stride = (long)gridDim.x * blockDim.x;
  for (; i < n4; i += stride) {
    float4 v = reinterpret_cast<const float4*>(in)[i];
    float am = fmaxf(fmaxf(fabsf(v.x), fabsf(v.y)), fmaxf(fabsf(v.z), fabsf(v.w)));
    am = fmaxf(am, __shfl_xor(am, 1));
    am = fmaxf(am, __shfl_xor(am, 2));
    am = fmaxf(am, __shfl_xor(am, 4));
    int se = ((am == 0.f) ? 0 : flog2(am)) - EMAX;
    se = se < -127 ? -127 : (se > 127 ? 127 : se);
    float inv = exp2i(-se), f = exp2i(se - se0);
    unsigned o = (unsigned)enc_rne(qelem<MFRAC>(v.x * inv, maxn) * f)
               | ((unsigned)enc_rne(qelem<MFRAC>(v.y * inv, maxn) * f) << 8)
               | ((unsigned)enc_rne(qelem<MFRAC>(v.z * inv, maxn) * f) << 16)
               | ((unsigned)enc_rne(qelem<MFRAC>(v.w * inv, maxn) * f) << 24);
    int row = (int)(i >> kshift);
    int kq = ((int)i & kmask) * 4;           // 4B stays inside the lane's 32B chunk
    reinterpret_cast<unsigned*>(out)[swz(row, kq, pa) >> 2] = o;
  }
}

__device__ __forceinline__ void gl_lds16(const unsigned char* g, unsigned char* l) {
  __builtin_amdgcn_global_load_lds(
      (const __attribute__((address_space(1))) void*)g,
      (__attribute__((address_space(3))) void*)l, 16, 0, 0);
}

// read one MFMA fragment from an LDS page (lane's 32B contiguous at page + l*32)
__device__ __forceinline__ i32x8 lfrag(const unsigned char* page, int l32) {
  return *reinterpret_cast<const i32x8*>(page + l32);
}

// ----- FUSED gate+up GEMM, 256x128 block, 8 waves (4Sx2I of 64x64, dual acc) --------
// LDS-staged A+Bg+Bu (32 pages x 2KB = 64KB, serial 2-barrier loop). Per-block
// traffic (256+128+128)*2048 = 1.0MB (vs 1.57MB at 128x128): -32% fabric traffic.
// silu(g)*u + fp6-MX requant in-register -> iq8 pages.
__global__ __launch_bounds__(512, 2) void mx_gateup(
    const unsigned char* __restrict__ A, int pa,
    const unsigned char* __restrict__ Bg, const unsigned char* __restrict__ Bu, int pb,
    unsigned char* __restrict__ C8, int ldC, float fac, int se0out) {
  __shared__ __align__(16) unsigned char lds[32 * 2048];  // A:0..15  Bg:16..23  Bu:24..31
  const int t = threadIdx.x, l = t & 63, w = t >> 6;
  const int sr = w >> 1, sc = w & 1;          // wave output 64x64 at (sr, sc)
  const int lr16 = l & 15, lg16 = l >> 4;
  const int l32 = l * 32;
  const int n = (int)blockIdx.x;               // grid 16 x 64 = 1024
  const int bx = n & 15, by = n >> 4;
  const int rowA = bx * 256 + sr * 64;         // wave's S rows
  const int rowB = by * 128 + sc * 64;         // wave's I cols
  const int SCL = 0x7f7f7f7f;  // e8m0 1.0 in every byte: scale path is a no-op

  f32x4 accg[4][4], accu[4][4];
#pragma unroll
  for (int i = 0; i < 4; ++i)
#pragma unroll
    for (int j = 0; j < 4; ++j) { accg[i][j] = (f32x4)(0.f); accu[i][j] = (f32x4)(0.f); }

  // staging: 4096 chunks of 16B (64KB); thread t stages chunks {t + i*512}.
  // chunk c -> page c>>7, intra (c&127)*16; pages map 1:1 to tensor pages.
  const unsigned char* gsrc[8];
  int dstb[8];
#pragma unroll
  for (int i = 0; i < 8; ++i) {
    int c = t + i * 512;
    int p = c >> 7, off = (c & 127) * 16;
    const unsigned char* base;
    if (p < 16) base = A + (size_t)(bx * 16 + p) * pa * 2048;
    else if (p < 24) base = Bg + (size_t)(by * 8 + (p - 16)) * pb * 2048;
    else base = Bu + (size_t)(by * 8 + (p - 24)) * pb * 2048;
    gsrc[i] = base + off;
    dstb[i] = c * 16;
  }

  const int nt = pa;  // K = 2048 -> 16 pages
  for (int kb = 0; kb < nt; ++kb) {
#pragma unroll
    for (int i = 0; i < 8; ++i) {
      gl_lds16(gsrc[i], &lds[dstb[i]]);
      gsrc[i] += 2048;
    }
    __syncthreads();
    i32x8 af[4], bg[4], bu[4];
#pragma unroll
    for (int m = 0; m < 4; ++m) af[m] = lfrag(&lds[(sr * 4 + m) * 2048], l32);
#pragma unroll
    for (int m = 0; m < 4; ++m) bg[m] = lfrag(&lds[(16 + sc * 4 + m) * 2048], l32);
#pragma unroll
    for (int m = 0; m < 4; ++m) bu[m] = lfrag(&lds[(24 + sc * 4 + m) * 2048], l32);
#pragma unroll
    for (int m = 0; m < 4; ++m)
#pragma unroll
      for (int nn = 0; nn < 4; ++nn) {
        accg[m][nn] = __builtin_amdgcn_mfma_scale_f32_16x16x128_f8f6f4(
            af[m], bg[nn], accg[m][nn], 0, 0, 0, SCL, 0, SCL);
        accu[m][nn] = __builtin_amdgcn_mfma_scale_f32_16x16x128_f8f6f4(
            af[m], bu[nn], accu[m][nn], 0, 0, 0, SCL, 0, SCL);
      }
    __syncthreads();
  }

  // epilogue: v = silu(g)*u, fp6-MX requant along 32-col blocks, fp8 out (pages)
  // 16x16 C/D layout: col = lane&15, row = (lane>>4)*4 + reg  (m89-verified)
  const int pao = ldC >> 7;
#pragma unroll
  for (int m = 0; m < 4; ++m)
#pragma unroll
    for (int p = 0; p < 2; ++p)
#pragma unroll
      for (int r = 0; r < 4; ++r) {
        int row = rowA + m * 16 + lg16 * 4 + r;
        int col = rowB + p * 32 + lr16;
        float g0 = accg[m][2 * p][r] * fac;
        float g1 = accg[m][2 * p + 1][r] * fac;
        float u0 = accu[m][2 * p][r] * fac;
        float u1 = accu[m][2 * p + 1][r] * fac;
        float v0 = u0 * (g0 / (1.f + expf(-g0)));
        float v1 = u1 * (g1 / (1.f + expf(-g1)));
        float am = fmaxf(fabsf(v0), fabsf(v1));
        am = fmaxf(am, __shfl_xor(am, 1));
        am = fmaxf(am, __shfl_xor(am, 2));
        am = fmaxf(am, __shfl_xor(am, 4));
        am = fmaxf(am, __shfl_xor(am, 8));
        int se = ((am == 0.f) ? 0 : flog2(am)) - 2;
        se = se < -127 ? -127 : (se > 127 ? 127 : se);
        float f = exp2i(-se), fo = exp2i(se - se0out);
        C8[swz(row, col, pao)] = enc_rne(qelem<3>(v0 * f, 7.5f) * fo);
        C8[swz(row, col + 16, pao)] = enc_rne(qelem<3>(v1 * f, 7.5f) * fo);
      }
}

// ----- down GEMM, 256x256 block, 8 waves (4Sx2I of 64x128, single acc), LDS-staged --
// K-split x2 -> grid 256 (1 block/CU). Per-block traffic (256+256)*4096 = 2MB over
// half-K (vs 1.5MB at 128x256 over half-K x2 blocks): -32% fabric traffic.
__global__ __launch_bounds__(512, 2) void mx_down(
    const unsigned char* __restrict__ A, int pa,
    const unsigned char* __restrict__ B, int pb,
    float* __restrict__ Cf, float* __restrict__ Cf2,
    int K, int ldC, float fac) {
  __shared__ __align__(16) unsigned char lds[32 * 2048];  // A:0..15  B:16..31
  const int t = threadIdx.x, l = t & 63, w = t >> 6;
  const int sr = w >> 1, sc = w & 1;          // wave tile 64x128 at (sr, sc)
  const int lr16 = l & 15, lg16 = l >> 4;
  const int l32 = l * 32;
  const int n = (int)blockIdx.x;               // grid 16 x 8 x 2 = 256
  const int bx = n & 15, rest = n >> 4;
  const int by = rest & 7, ks = rest >> 3;
  const int rowA = bx * 256 + sr * 64;
  const int rowB = by * 256 + sc * 128;
  const int kbs = ks * (K >> 7);
  const int SCL = 0x7f7f7f7f;

  f32x4 acc[4][8];
#pragma unroll
  for (int i = 0; i < 4; ++i)
#pragma unroll
    for (int j = 0; j < 8; ++j) acc[i][j] = (f32x4)(0.f);

  const unsigned char* gsrc[8];
  int dstb[8];
#pragma unroll
  for (int i = 0; i < 8; ++i) {
    int c = t + i * 512;
    int p = c >> 7, off = (c & 127) * 16;
    const unsigned char* base;
    if (p < 16) base = A + ((size_t)(bx * 16 + p) * pa + kbs) * 2048;
    else base = B + ((size_t)(by * 16 + (p - 16)) * pb + kbs) * 2048;
    gsrc[i] = base + off;
    dstb[i] = c * 16;
  }

  const int nt = K >> 7;  // 32 pages per half
  for (int kb = 0; kb < nt; ++kb) {
#pragma unroll
    for (int i = 0; i < 8; ++i) {
      gl_lds16(gsrc[i], &lds[dstb[i]]);
      gsrc[i] += 2048;
    }
    __syncthreads();
    i32x8 af[4], bf[8];
#pragma unroll
    for (int m = 0; m < 4; ++m) af[m] = lfrag(&lds[(sr * 4 + m) * 2048], l32);
#pragma unroll
    for (int nn = 0; nn < 8; ++nn) bf[nn] = lfrag(&lds[(16 + sc * 8 + nn) * 2048], l32);
#pragma unroll
    for (int m = 0; m < 4; ++m)
#pragma unroll
      for (int nn = 0; nn < 8; ++nn)
        acc[m][nn] = __builtin_amdgcn_mfma_scale_f32_16x16x128_f8f6f4(
            af[m], bf[nn], acc[m][nn], 0, 0, 0, SCL, 0, SCL);
    __syncthreads();
  }

  float* D = ks ? Cf2 : Cf;
#pragma unroll
  for (int m = 0; m < 4; ++m)
#pragma unroll
    for (int nn = 0; nn < 8; ++nn)
#pragma unroll
      for (int r = 0; r < 4; ++r) {
        int row = rowA + m * 16 + lg16 * 4 + r;
        int col = rowB + nn * 16 + lr16;
        D[(size_t)row * ldC + col] = acc[m][nn][r] * fac;
      }
}

__global__ void add_f32(float* __restrict__ out, const float* __restrict__ part, long n4) {
  long i = (long)blockIdx.x * blockDim.x + threadIdx.x;
  long stride = (long)gridDim.x * blockDim.x;
  for (; i < n4; i += stride) {
    float4 a = reinterpret_cast<float4*>(out)[i];
    float4 b = reinterpret_cast<const float4*>(part)[i];
    a.x += b.x; a.y += b.y; a.z += b.z; a.w += b.w;
    reinterpret_cast<float4*>(out)[i] = a;
  }
}

extern "C" void kernel_launch(void* const* d_in, const int* in_sizes, int n_in,
                              void* d_out, int out_size, void* d_ws, size_t ws_size,
                              hipStream_t stream) {
  const float* x = (const float*)d_in[0];
  const float* wg = (const float*)d_in[1];
  const float* wu = (const float*)d_in[2];
  const float* wd = (const float*)d_in[3];
  float* out = (float*)d_out;

  const int S = 4096, H = 2048, I = 8192;

  // per-tensor fold baselines: exact while block se in [se0-6, se0+5]
  const int SE0X = -1, SE0W = -7, SE0I = -2;
  const float FAC_GU = 0.00390625f;     // 2^(SE0X + SE0W) = 2^-8
  const float FAC_DN = 0.001953125f;    // 2^(SE0I + SE0W) = 2^-9

  unsigned char* p = (unsigned char*)d_ws;
  unsigned char* xq8 = p;  p += (size_t)S * H;   //  8.4 MB (swizzled pages)
  unsigned char* wgq8 = p; p += (size_t)I * H;   // 16.8 MB
  unsigned char* wuq8 = p; p += (size_t)I * H;   // 16.8 MB
  unsigned char* wdq8 = p; p += (size_t)H * I;   // 16.8 MB
  unsigned char* iq8 = p;  p += (size_t)S * I;   // 33.6 MB
  float* pf = (float*)p;                         // down K-split partial, 33.6 MB

  // quantize -> fragment-page-swizzled e4m3
  quant_fold<3, 2><<<2048, 256, 0, stream>>>(x, xq8, (long)S * H / 4, 7.5f, SE0X,
                                             9, 511, H / 128);    // K=2048
  quant_fold<1, 2><<<2048, 256, 0, stream>>>(wg, wgq8, (long)I * H / 4, 6.0f, SE0W,
                                             9, 511, H / 128);
  quant_fold<1, 2><<<2048, 256, 0, stream>>>(wu, wuq8, (long)I * H / 4, 6.0f, SE0W,
                                             9, 511, H / 128);
  quant_fold<1, 2><<<2048, 256, 0, stream>>>(wd, wdq8, (long)H * I / 4, 6.0f, SE0W,
                                             11, 2047, I / 128);  // K=8192

  // fused gate+up + SwiGLU + fp6-MX requant -> iq8 pages (grid 16 x 64 = 1024)
  mx_gateup<<<16 * (I / 128), 512, 0, stream>>>(
      xq8, H / 128, wgq8, wuq8, H / 128, iq8, I, FAC_GU, SE0I);

  // down GEMM, K split in 2 (grid 16*8*2 = 256)
  mx_down<<<256, 512, 0, stream>>>(
      iq8, I / 128, wdq8, I / 128, out, pf, I / 2, H, FAC_DN);
  add_f32<<<2048, 256, 0, stream>>>(out, pf, (long)S * H / 4);
}

// Round 26
// 410.716 us; speedup vs baseline: 1.1091x; 1.1091x over previous
//
#include <hip/hip_runtime.h>
#include <hip/hip_bf16.h>

typedef __attribute__((ext_vector_type(4))) int i32x4;
typedef __attribute__((ext_vector_type(8))) int i32x8;
typedef __attribute__((ext_vector_type(4))) float f32x4;

// exact floor(log2(x)) for x > 0 (handles subnormals)
__device__ __forceinline__ int flog2(float x) {
  unsigned u = __float_as_uint(x);
  int e = (int)((u >> 23) & 255u);
  if (e) return e - 127;
  unsigned m = u & 0x7fffffu;
  return (31 - __clz(m)) - 149;
}

// exact 2^e for e in [-252, 254]
__device__ __forceinline__ float exp2i(int e) {
  int e1 = e >> 1, e2 = e - e1;
  return __uint_as_float((unsigned)(e1 + 127) << 23) *
         __uint_as_float((unsigned)(e2 + 127) << 23);
}

// quantize y (already divided by shared scale) to e2m<MFRAC>, round-half-even, saturate
template <int MFRAC>
__device__ __forceinline__ float qelem(float y, float maxn) {
  float ay = fabsf(y);
  int e = (ay == 0.f) ? 0 : flog2(ay);
  if (e < 0) e = 0;  // min_exp = 0 for ebits=2
  float r = rintf(y * exp2i(MFRAC - e)) * exp2i(e - MFRAC);
  return fminf(fmaxf(r, -maxn), maxn);
}

// general RNE fp32 -> OCP e4m3 encode (|v| <= 448; exact on our folded value grid)
__device__ __forceinline__ unsigned char enc_rne(float v) {
  unsigned u = __float_as_uint(v);
  unsigned s = u >> 31;
  float a = fabsf(v);
  if (a == 0.f) return (unsigned char)(s << 7);
  int e = flog2(a);
  if (e < -6) e = -6;                      // subnormal regime
  int qi = (int)rintf(a * exp2i(3 - e));   // RNE to 3-frac-bit grid -> [0,16]
  if (qi == 0) return (unsigned char)(s << 7);
  if (qi == 16) { qi = 8; e += 1; }
  unsigned exf, m;
  if (qi < 8) { exf = 0u; m = (unsigned)qi; }          // e == -6 subnormal
  else { exf = (unsigned)(e + 7); m = (unsigned)(qi - 8); }
  return (unsigned char)((s << 7) | (exf << 3) | m);
}

// fragment-page swizzle (CONTIGUOUS-LANE layout): 2KB page per (16-row x 128-K block);
// lane l = (row&15) + ((k>>5)&3)*16 holds k-bytes [ (l>>4)*32 , +32 ) CONTIGUOUSLY at
// page + l*32. pa = K/128 pages per row-block.
__device__ __forceinline__ size_t swz(int row, int col, int pa) {
  return ((size_t)((row >> 4) * pa + (col >> 7))) * 2048
       + (size_t)((((row & 15) + (((col >> 5) & 3) << 4)) << 5) + (col & 31));
}

// ------ MX quantization with exponent folding -> fragment-page-swizzled e4m3 bytes ---
template <int MFRAC, int EMAX>
__global__ void quant_fold(const float* __restrict__ in, unsigned char* __restrict__ out,
                           long n4, float maxn, int se0, int kshift, int kmask, int pa) {
  long i = (long)blockIdx.x * blockDim.x + threadIdx.x;
  long stride = (long)gridDim.x * blockDim.x;
  for (; i < n4; i += stride) {
    float4 v = reinterpret_cast<const float4*>(in)[i];
    float am = fmaxf(fmaxf(fabsf(v.x), fabsf(v.y)), fmaxf(fabsf(v.z), fabsf(v.w)));
    am = fmaxf(am, __shfl_xor(am, 1));
    am = fmaxf(am, __shfl_xor(am, 2));
    am = fmaxf(am, __shfl_xor(am, 4));
    int se = ((am == 0.f) ? 0 : flog2(am)) - EMAX;
    se = se < -127 ? -127 : (se > 127 ? 127 : se);
    float inv = exp2i(-se), f = exp2i(se - se0);
    unsigned o = (unsigned)enc_rne(qelem<MFRAC>(v.x * inv, maxn) * f)
               | ((unsigned)enc_rne(qelem<MFRAC>(v.y * inv, maxn) * f) << 8)
               | ((unsigned)enc_rne(qelem<MFRAC>(v.z * inv, maxn) * f) << 16)
               | ((unsigned)enc_rne(qelem<MFRAC>(v.w * inv, maxn) * f) << 24);
    int row = (int)(i >> kshift);
    int kq = ((int)i & kmask) * 4;           // 4B stays inside the lane's 32B chunk
    reinterpret_cast<unsigned*>(out)[swz(row, kq, pa) >> 2] = o;
  }
}

// load one MFMA fragment: lane's 32B is CONTIGUOUS -> single i32x8 load
__device__ __forceinline__ i32x8 gfrag(const unsigned char* page, int l32) {
  return *reinterpret_cast<const i32x8*>(page + l32);
}

// ----- FUSED gate+up GEMM, 16x16x128 MFMA, NO LDS / NO BARRIERS -------------------
// Block 128x128 (S x I), 4 waves (2x2 of 64x64 output, DUAL accumulators).
// Per K-step: 12 gfrag (4 A shared + 4 Bg + 4 Bu) feed 32 MFMAs (16 gate + 16 up).
// silu(g)*u + fp6-MX requant in-register -> iq8 pages; gate never touches memory.
// unroll 4: folds page offsets into load immediates, batches pointer advances.
__global__ __launch_bounds__(256, 2) void mx_gateup(
    const unsigned char* __restrict__ A, int pa,
    const unsigned char* __restrict__ Bg, const unsigned char* __restrict__ Bu, int pb,
    unsigned char* __restrict__ C8, int ldC, float fac, int se0out, int nby) {
  const int t = threadIdx.x, l = t & 63, w = t >> 6;
  const int wr = w >> 1, wc = w & 1;          // 2x2 wave grid; wave output 64x64
  const int lr16 = l & 15, lg16 = l >> 4;
  const int l32 = l * 32;
  const int n = (int)blockIdx.x;
  const int bx = n % 32, by = n / 32;          // 32 x nby grid
  const int rowA = bx * 128, rowB = by * 128;
  const int SCL = 0x7f7f7f7f;  // e8m0 1.0 in every byte: scale path is a no-op

  f32x4 accg[4][4], accu[4][4];
#pragma unroll
  for (int i = 0; i < 4; ++i)
#pragma unroll
    for (int j = 0; j < 4; ++j) { accg[i][j] = (f32x4)(0.f); accu[i][j] = (f32x4)(0.f); }

  const unsigned char* pApg[4];
  const unsigned char* pBg[4];
  const unsigned char* pBu[4];
#pragma unroll
  for (int m = 0; m < 4; ++m) {
    pApg[m] = A + (size_t)((rowA >> 4) + wr * 4 + m) * pa * 2048;
    pBg[m] = Bg + (size_t)((rowB >> 4) + wc * 4 + m) * pb * 2048;
    pBu[m] = Bu + (size_t)((rowB >> 4) + wc * 4 + m) * pb * 2048;
  }

  const int nt = pa;  // K = 2048 -> 16 pages
#pragma unroll 4
  for (int kb = 0; kb < nt; ++kb) {
    i32x8 af[4], bg[4], bu[4];
#pragma unroll
    for (int m = 0; m < 4; ++m) { af[m] = gfrag(pApg[m], l32); pApg[m] += 2048; }
#pragma unroll
    for (int m = 0; m < 4; ++m) { bg[m] = gfrag(pBg[m], l32); pBg[m] += 2048; }
#pragma unroll
    for (int m = 0; m < 4; ++m) { bu[m] = gfrag(pBu[m], l32); pBu[m] += 2048; }
#pragma unroll
    for (int m = 0; m < 4; ++m)
#pragma unroll
      for (int nn = 0; nn < 4; ++nn) {
        accg[m][nn] = __builtin_amdgcn_mfma_scale_f32_16x16x128_f8f6f4(
            af[m], bg[nn], accg[m][nn], 0, 0, 0, SCL, 0, SCL);
        accu[m][nn] = __builtin_amdgcn_mfma_scale_f32_16x16x128_f8f6f4(
            af[m], bu[nn], accu[m][nn], 0, 0, 0, SCL, 0, SCL);
      }
  }

  // epilogue: v = silu(g)*u, fp6-MX requant along 32-col blocks, fp8 out (pages)
  // 16x16 C/D layout: col = lane&15, row = (lane>>4)*4 + reg  (m89-verified)
  const int pao = ldC >> 7;
#pragma unroll
  for (int m = 0; m < 4; ++m)
#pragma unroll
    for (int p = 0; p < 2; ++p)
#pragma unroll
      for (int r = 0; r < 4; ++r) {
        int row = rowA + wr * 64 + m * 16 + lg16 * 4 + r;
        int col = rowB + wc * 64 + p * 32 + lr16;
        float g0 = accg[m][2 * p][r] * fac;
        float g1 = accg[m][2 * p + 1][r] * fac;
        float u0 = accu[m][2 * p][r] * fac;
        float u1 = accu[m][2 * p + 1][r] * fac;
        float v0 = u0 * (g0 / (1.f + expf(-g0)));
        float v1 = u1 * (g1 / (1.f + expf(-g1)));
        float am = fmaxf(fabsf(v0), fabsf(v1));
        am = fmaxf(am, __shfl_xor(am, 1));
        am = fmaxf(am, __shfl_xor(am, 2));
        am = fmaxf(am, __shfl_xor(am, 4));
        am = fmaxf(am, __shfl_xor(am, 8));
        int se = ((am == 0.f) ? 0 : flog2(am)) - 2;
        se = se < -127 ? -127 : (se > 127 ? 127 : se);
        float f = exp2i(-se), fo = exp2i(se - se0out);
        C8[swz(row, col, pao)] = enc_rne(qelem<3>(v0 * f, 7.5f) * fo);
        C8[swz(row, col + 16, pao)] = enc_rne(qelem<3>(v1 * f, 7.5f) * fo);
      }
}

// ----- down GEMM (R17 structure): wave tile 64x128, fp32 out, K-split via Cf/Cf2 ----
__global__ __launch_bounds__(256, 2) void mx_down(
    const unsigned char* __restrict__ A, int pa,
    const unsigned char* __restrict__ B, int pb,
    float* __restrict__ Cf, float* __restrict__ Cf2,
    int K, int ldC, float fac, int nby) {
  const int t = threadIdx.x, l = t & 63, w = t >> 6;
  const int wr = w >> 1, wc = w & 1;          // 2x2 wave grid; wave tile 64x128
  const int lr16 = l & 15, lg16 = l >> 4;
  const int l32 = l * 32;
  const int n = (int)blockIdx.x;
  const int bx = n & 31, byks = n >> 5;
  const int by = byks % nby, ks = byks / nby;
  const int rowA = bx * 128, rowB = by * 256;
  const int kbs = ks * (K >> 7);
  const int SCL = 0x7f7f7f7f;

  f32x4 acc[4][8];
#pragma unroll
  for (int i = 0; i < 4; ++i)
#pragma unroll
    for (int j = 0; j < 8; ++j) acc[i][j] = (f32x4)(0.f);

  const unsigned char* pApg[4];
  const unsigned char* pBpg[8];
#pragma unroll
  for (int m = 0; m < 4; ++m)
    pApg[m] = A + ((size_t)((rowA >> 4) + wr * 4 + m) * pa + kbs) * 2048;
#pragma unroll
  for (int nn = 0; nn < 8; ++nn)
    pBpg[nn] = B + ((size_t)((rowB >> 4) + wc * 8 + nn) * pb + kbs) * 2048;

  const int nt = K >> 7;
#pragma unroll 4
  for (int kb = 0; kb < nt; ++kb) {
    i32x8 af[4], bf[8];
#pragma unroll
    for (int m = 0; m < 4; ++m) { af[m] = gfrag(pApg[m], l32); pApg[m] += 2048; }
#pragma unroll
    for (int nn = 0; nn < 8; ++nn) { bf[nn] = gfrag(pBpg[nn], l32); pBpg[nn] += 2048; }
#pragma unroll
    for (int m = 0; m < 4; ++m)
#pragma unroll
      for (int nn = 0; nn < 8; ++nn)
        acc[m][nn] = __builtin_amdgcn_mfma_scale_f32_16x16x128_f8f6f4(
            af[m], bf[nn], acc[m][nn], 0, 0, 0, SCL, 0, SCL);
  }

  float* D = ks ? Cf2 : Cf;
#pragma unroll
  for (int m = 0; m < 4; ++m)
#pragma unroll
    for (int nn = 0; nn < 8; ++nn)
#pragma unroll
      for (int r = 0; r < 4; ++r) {
        int row = rowA + wr * 64 + m * 16 + lg16 * 4 + r;
        int col = rowB + wc * 128 + nn * 16 + lr16;
        D[(size_t)row * ldC + col] = acc[m][nn][r] * fac;
      }
}

__global__ void add_f32(float* __restrict__ out, const float* __restrict__ part, long n4) {
  long i = (long)blockIdx.x * blockDim.x + threadIdx.x;
  long stride = (long)gridDim.x * blockDim.x;
  for (; i < n4; i += stride) {
    float4 a = reinterpret_cast<float4*>(out)[i];
    float4 b = reinterpret_cast<const float4*>(part)[i];
    a.x += b.x; a.y += b.y; a.z += b.z; a.w += b.w;
    reinterpret_cast<float4*>(out)[i] = a;
  }
}

extern "C" void kernel_launch(void* const* d_in, const int* in_sizes, int n_in,
                              void* d_out, int out_size, void* d_ws, size_t ws_size,
                              hipStream_t stream) {
  const float* x = (const float*)d_in[0];
  const float* wg = (const float*)d_in[1];
  const float* wu = (const float*)d_in[2];
  const float* wd = (const float*)d_in[3];
  float* out = (float*)d_out;

  const int S = 4096, H = 2048, I = 8192;

  // per-tensor fold baselines: exact while block se in [se0-6, se0+5]
  const int SE0X = -1, SE0W = -7, SE0I = -2;
  const float FAC_GU = 0.00390625f;     // 2^(SE0X + SE0W) = 2^-8
  const float FAC_DN = 0.001953125f;    // 2^(SE0I + SE0W) = 2^-9

  unsigned char* p = (unsigned char*)d_ws;
  unsigned char* xq8 = p;  p += (size_t)S * H;   //  8.4 MB (swizzled pages)
  unsigned char* wgq8 = p; p += (size_t)I * H;   // 16.8 MB
  unsigned char* wuq8 = p; p += (size_t)I * H;   // 16.8 MB
  unsigned char* wdq8 = p; p += (size_t)H * I;   // 16.8 MB
  unsigned char* iq8 = p;  p += (size_t)S * I;   // 33.6 MB
  float* pf = (float*)p;                         // down K-split partial, 33.6 MB

  // quantize -> fragment-page-swizzled e4m3
  quant_fold<3, 2><<<2048, 256, 0, stream>>>(x, xq8, (long)S * H / 4, 7.5f, SE0X,
                                             9, 511, H / 128);    // K=2048
  quant_fold<1, 2><<<2048, 256, 0, stream>>>(wg, wgq8, (long)I * H / 4, 6.0f, SE0W,
                                             9, 511, H / 128);
  quant_fold<1, 2><<<2048, 256, 0, stream>>>(wu, wuq8, (long)I * H / 4, 6.0f, SE0W,
                                             9, 511, H / 128);
  quant_fold<1, 2><<<2048, 256, 0, stream>>>(wd, wdq8, (long)H * I / 4, 6.0f, SE0W,
                                             11, 2047, I / 128);  // K=8192

  // fused gate+up + SwiGLU + fp6-MX requant -> iq8 pages (grid 32 x 64 = 2048)
  mx_gateup<<<32 * (I / 128), 256, 0, stream>>>(
      xq8, H / 128, wgq8, wuq8, H / 128, iq8, I, FAC_GU, SE0I, I / 128);

  // down GEMM, K split in 2 (K = I/2 per half; grid 32*8*2 = 512)
  mx_down<<<32 * (H / 256) * 2, 256, 0, stream>>>(
      iq8, I / 128, wdq8, I / 128, out, pf, I / 2, H, FAC_DN, H / 256);
  add_f32<<<2048, 256, 0, stream>>>(out, pf, (long)S * H / 4);
}